// Round 14
// baseline (578.527 us; speedup 1.0000x reference)
//
#include <hip/hip_runtime.h>
#include <hip/hip_bf16.h>
#include <math.h>

#define N_NODES 30000
#define M_P     4
#define E_EDGES 480000
#define N_TOK   (N_NODES * 4)
#define N_ROWS  (M_P * N_NODES)      // 120000 (m,src) rows
#define SLOTS   30                   // per-row bin slots; row = 64B: [int cnt | 30 ushort]
#define OVF_CAP 65536                // overflow list capacity (never used in practice)
#define LN_EPS  1e-5f

#define NB_FILL 1875                 // fill blocks (M*E / 1024)
#define NB_LIN  3752                 // lin blocks (469 x 8)

typedef short bf16x8 __attribute__((ext_vector_type(8)));
typedef float f32x4  __attribute__((ext_vector_type(4)));
#define MFMA_B16(a, b, c) __builtin_amdgcn_mfma_f32_16x16x32_bf16(a, b, c, 0, 0, 0)

__device__ inline unsigned short f2bf(float f) {
    union { float f; unsigned u; } v; v.f = f;
    unsigned r = v.u + 0x7fffu + ((v.u >> 16) & 1u);
    return (unsigned short)(r >> 16);
}
// HW packed cvt (v_cvt_pk_bf16_f32, RNE — same rounding as f2bf)
__device__ inline unsigned pack2bf(float a, float b) {
    union { __hip_bfloat162 h; unsigned u; } cv;
    cv.h = __float22bfloat162_rn(make_float2(a, b));
    return cv.u;
}
__device__ inline float bf2f(short s) {
    union { unsigned u; float f; } v; v.u = ((unsigned)(unsigned short)s) << 16;
    return v.f;
}
// Build a B-fragment (8 contiguous k-elements of one token) directly from two float4s
__device__ inline bf16x8 mk_frag(const float4& a, const float4& b) {
    union { uint4 u; bf16x8 v; } cv;
    cv.u = make_uint4(pack2bf(a.x, a.y), pack2bf(a.z, a.w),
                      pack2bf(b.x, b.y), pack2bf(b.z, b.w));
    return cv.v;
}

// ===================== Phase A mega-kernel: fill (critical path, first) + lin MFMA =====================
__global__ __launch_bounds__(256) void k_phaseA(
    const int* __restrict__ ei, unsigned short* __restrict__ bins,
    int* __restrict__ ovf_cnt, int2* __restrict__ ovf,
    const float* __restrict__ x,
    const float* __restrict__ Wl, const float* __restrict__ W0, const float* __restrict__ W1,
    const float* __restrict__ b0, const float* __restrict__ bl, const float* __restrict__ b1,
    unsigned short* __restrict__ ybf, unsigned short* __restrict__ zbf)
{
    __shared__ __align__(16) short Wf[8192];    // 16 KB weight frags (lin blocks only)
    const int bid = blockIdx.x;
    const int t = threadIdx.x;

    if (bid < NB_FILL) {
        // ---------------- fill: 4 edges/thread ----------------
        const int base = bid * 1024 + t;
        int rows[4], dsts[4];
        #pragma unroll
        for (int i = 0; i < 4; ++i) {
            const int g = base + i * 256;               // coalesced per i
            const int m = g / E_EDGES;
            const int e = g - m * E_EDGES;
            rows[i] = m * N_NODES + ei[(m * 2) * E_EDGES + e];
            dsts[i] = ei[(m * 2 + 1) * E_EDGES + e];
        }
        int pos[4];
        #pragma unroll
        for (int i = 0; i < 4; ++i)
            pos[i] = atomicAdd((int*)bins + rows[i] * 16, 1);   // header int of the 64B bin
        #pragma unroll
        for (int i = 0; i < 4; ++i) {
            if (pos[i] < SLOTS) {
                bins[rows[i] * 32 + 2 + pos[i]] = (unsigned short)dsts[i];
            } else {                                    // statistically never taken
                const int ix = atomicAdd(ovf_cnt, 1);
                if (ix < OVF_CAP) ovf[ix] = make_int2(rows[i], dsts[i]);
            }
        }
    } else {
        // ---------------- lin: y = x@Wl^T ; z = x@(W0+W1)^T + biases (bf16 out) ----------------
        const int lid = bid - NB_FILL;
        const int bx = lid % 469;
        const int by = lid / 469;                       // 0..7 = which*4+m
        const int which = by >> 2, m = by & 3;
        const int w = t >> 6, lane = t & 63;
        const int m_ = lane & 15, qc = lane >> 4;
        const int node = bx * 64 + w * 16 + m_;

        #pragma unroll
        for (int i = 0; i < 32; ++i) {
            const int d = t + 256 * i;                  // [0, 8192)
            const int fg = d >> 9, rem = d & 511;
            const int qmm = rem >> 3, j = d & 7;
            const int q = qmm >> 4, mm = qmm & 15;
            const int ot = fg >> 2, hh = fg & 3;
            const int row = ot * 16 + mm, k = hh * 32 + q * 8 + j;
            float v;
            if (which == 0) v = Wl[(m * 64 + row) * 128 + k];
            else            v = W0[(m * 64 + row) * 128 + k] + W1[(m * 64 + row) * 128 + k];
            Wf[d] = (short)f2bf(v);
        }

        bf16x8 xb[4];
        #pragma unroll
        for (int hh = 0; hh < 4; ++hh) {
            float4 a = make_float4(0.f, 0.f, 0.f, 0.f), b = a;
            if (node < N_NODES) {
                a = *(const float4*)(x + node * 128 + hh * 32 + qc * 8);
                b = *(const float4*)(x + node * 128 + hh * 32 + qc * 8 + 4);
            }
            xb[hh] = mk_frag(a, b);
        }
        __syncthreads();

        f32x4 acc[4];
        #pragma unroll
        for (int ot = 0; ot < 4; ++ot) {
            f32x4 c = {};
            if (which) {
                const int o = m * 64 + ot * 16 + qc * 4;
                const float4 v0 = *(const float4*)(b0 + o);
                const float4 v1 = *(const float4*)(b1 + o);
                const float4 vl = *(const float4*)(bl + o);
                c[0] = v0.x + v1.x + vl.x; c[1] = v0.y + v1.y + vl.y;
                c[2] = v0.z + v1.z + vl.z; c[3] = v0.w + v1.w + vl.w;
            }
            #pragma unroll
            for (int hh = 0; hh < 4; ++hh) {
                const bf16x8 wa = *(const bf16x8*)&Wf[(ot * 4 + hh) * 512 + lane * 8];
                c = MFMA_B16(wa, xb[hh], c);
            }
            acc[ot] = c;
        }
        unsigned short* outp = which ? zbf : ybf;
        if (node < N_NODES) {
            #pragma unroll
            for (int ot = 0; ot < 4; ++ot) {
                uint2 pk = make_uint2(pack2bf(acc[ot][0], acc[ot][1]),
                                      pack2bf(acc[ot][2], acc[ot][3]));
                *(uint2*)(outp + ((size_t)m * N_NODES + node) * 64 + ot * 16 + qc * 4) = pk;
            }
        }
    }
}

// ===================== Gather-reduce — one wave per (m,src) row; 4-way ILP; bf16 y =====================
__global__ __launch_bounds__(256) void k_gather(
    const unsigned short* __restrict__ bins,
    const int* __restrict__ ovf_cnt, const int2* __restrict__ ovf,
    const unsigned short* __restrict__ ybf, float* __restrict__ aggh)
{
    const int w = threadIdx.x >> 6, lane = threadIdx.x & 63;
    const int row = blockIdx.x * 4 + w;                 // < N_ROWS
    const int m = row / N_NODES;
    const unsigned short* ym = ybf + (size_t)m * N_NODES * 64;
    const int v = (lane < 32) ? bins[row * 32 + lane] : 0;  // lanes 0,1 = header halves
    const int v0 = __shfl(v, 0), v1 = __shfl(v, 1);
    const int tot = (v0 & 0xffff) | (v1 << 16);
    const int cnt = min(tot, SLOTS);
    float a0 = 0.f, a1 = 0.f, a2 = 0.f, a3 = 0.f;
    int j = 0;
    for (; j + 4 <= cnt; j += 4) {
        const int r0 = __shfl(v, j + 2), r1 = __shfl(v, j + 3);
        const int r2 = __shfl(v, j + 4), r3 = __shfl(v, j + 5);
        a0 += bf2f((short)ym[r0 * 64 + lane]); a1 += bf2f((short)ym[r1 * 64 + lane]);
        a2 += bf2f((short)ym[r2 * 64 + lane]); a3 += bf2f((short)ym[r3 * 64 + lane]);
    }
    for (; j < cnt; ++j) {
        const int r = __shfl(v, j + 2);
        a0 += bf2f((short)ym[r * 64 + lane]);
    }
    if (tot > SLOTS) {                                  // statistically never taken
        const int no = min(*ovf_cnt, OVF_CAP);
        for (int i2 = 0; i2 < no; ++i2) {
            const int2 ent = ovf[i2];
            if (ent.x == row) a0 += bf2f((short)ym[ent.y * 64 + lane]);
        }
    }
    aggh[(size_t)row * 64 + lane] = (a0 + a1) + (a2 + a3);
}

// ===================== emb + transformer weight shuffle (merged; y region dead by now) ==========
__global__ __launch_bounds__(256) void k_emb_ws(
    const float* __restrict__ aggh, const unsigned short* __restrict__ zbf,
    const float* __restrict__ Wo, const float* __restrict__ bo,
    const float* __restrict__ mpw, float* __restrict__ e,
    const float* __restrict__ ff1w, const float* __restrict__ ff2w,
    const float* __restrict__ tinw, const float* __restrict__ tow,
    unsigned short* __restrict__ w1s, unsigned short* __restrict__ w2s,
    unsigned short* __restrict__ wqkv_s, unsigned short* __restrict__ tow_s)
{
    __shared__ float hT[64][20];
    __shared__ float WoT[64][64];
    const int t = threadIdx.x;
    const int bid = blockIdx.x;

    if (bid >= N_NODES / 16) {
        const int g = (bid - N_NODES / 16) * 256 + t;   // [0, 262144)
        {
            const int l = g >> 17, r2 = g & 131071;
            const int f = r2 >> 6, k = r2 & 63;
            const int c = f >> 6, fc = f & 63, ft = fc >> 4, m = fc & 15;
            const int h = k >> 5, q = (k >> 3) & 3, j = k & 7;
            w1s[l * 131072 + c * 4096 + (ft * 2 + h) * 512 + (q * 16 + m) * 8 + j] = f2bf(ff1w[g]);
        }
        {
            const int l = g >> 17, r2 = g & 131071;
            const int o = r2 >> 11, f = r2 & 2047;
            const int c = f >> 6, fc = f & 63, h = fc >> 5, q = (fc >> 3) & 3, j = fc & 7;
            const int ot = o >> 4, m = o & 15;
            w2s[l * 131072 + c * 4096 + (ot * 2 + h) * 512 + (q * 16 + m) * 8 + j] = f2bf(ff2w[g]);
        }
        if (g < 2 * 192 * 64) {
            const int l = g / 12288, r2 = g - l * 12288;
            const int f = r2 >> 6, k = r2 & 63;
            const int ft = f >> 4, m = f & 15;
            const int h = k >> 5, q = (k >> 3) & 3, j = k & 7;
            wqkv_s[l * 12288 + (ft * 2 + h) * 512 + (q * 16 + m) * 8 + j] = f2bf(tinw[g]);
        }
        if (g < 2 * 64 * 64) {
            const int l = g >> 12, r2 = g & 4095;
            const int o = r2 >> 6, k = r2 & 63;
            const int ot = o >> 4, m = o & 15;
            const int h = k >> 5, q = (k >> 3) & 3, j = k & 7;
            tow_s[l * 4096 + (ot * 2 + h) * 512 + (q * 16 + m) * 8 + j] = f2bf(tow[g]);
        }
        return;
    }

    const int node0 = bid * 16;
    for (int m = 0; m < 4; ++m) {
        #pragma unroll
        for (int i = 0; i < 4; ++i) {
            const int o  = (t & 15) + 16 * i;
            const int kq = t >> 4;
            const float4 v = *(const float4*)(Wo + (m * 64 + o) * 64 + kq * 4);
            WoT[kq * 4 + 0][o] = v.x; WoT[kq * 4 + 1][o] = v.y;
            WoT[kq * 4 + 2][o] = v.z; WoT[kq * 4 + 3][o] = v.w;
        }
        {
            const int node = t & 15, kq = t >> 4;
            const int n = node0 + node;
            const float4 a = *(const float4*)(aggh + ((size_t)m * N_NODES + n) * 64 + kq * 4);
            const uint2 bz = *(const uint2*)(zbf + ((size_t)m * N_NODES + n) * 64 + kq * 4);
            hT[kq * 4 + 0][node] = fmaxf(a.x + bf2f((short)(bz.x & 0xffff)), 0.f);
            hT[kq * 4 + 1][node] = fmaxf(a.y + bf2f((short)(bz.x >> 16)), 0.f);
            hT[kq * 4 + 2][node] = fmaxf(a.z + bf2f((short)(bz.y & 0xffff)), 0.f);
            hT[kq * 4 + 3][node] = fmaxf(a.w + bf2f((short)(bz.y >> 16)), 0.f);
        }
        __syncthreads();
        const int o = t & 63, nl4 = (t >> 6) * 4;
        float acc[4] = {};
        #pragma unroll 8
        for (int k = 0; k < 64; ++k) {
            const float bw = WoT[k][o];
            const float4 a = *(const float4*)&hT[k][nl4];
            acc[0] += a.x * bw; acc[1] += a.y * bw; acc[2] += a.z * bw; acc[3] += a.w * bw;
        }
        const float bb = bo[m * 64 + o];
        const float w  = mpw[m];
        #pragma unroll
        for (int i = 0; i < 4; ++i)
            e[((node0 + nl4 + i) * 4 + m) * 64 + o] = (acc[i] + bb) * w;
        __syncthreads();
    }
}

// ===================== Fused transformer layer: attn + LN1 + FFN + LN2 in one kernel ==========
// Attn phase uses U as [w]QK(4352) | [w]V(2304) (52 KB). After a phase barrier, the same LDS
// is reused as Wb(8192) | [w]Act(2048). LN1 output crosses phases in registers (residual) and
// via an Act-slab frag transpose (FFN X input). Numerically identical to the split kernels.
__global__ __launch_bounds__(256, 3) void k_layer(
    const float* __restrict__ e,
    const unsigned short* __restrict__ wqkv_s, const float* __restrict__ tinb,
    const unsigned short* __restrict__ tow_s, const float* __restrict__ tob,
    const float* __restrict__ ln1g, const float* __restrict__ ln1b,
    const unsigned short* __restrict__ w1s, const unsigned short* __restrict__ w2s,
    const float* __restrict__ ff1b, const float* __restrict__ ff2b,
    const float* __restrict__ ln2g, const float* __restrict__ ln2b,
    float* __restrict__ eout, int l)
{
    __shared__ __align__(16) short U[26624];     // 52 KB union
    const int t = threadIdx.x;
    const int w = t >> 6, lane = t & 63;
    const int m_ = lane & 15, qc = lane >> 4;
    const int tok0 = blockIdx.x * 128;
    short* QKw = &U[w * 4352];
    short* Vw  = &U[17408 + w * 2304];

    // ================= attention =================
    bf16x8 xb[2][2];
    #pragma unroll
    for (int nt = 0; nt < 2; ++nt)
        #pragma unroll
        for (int h = 0; h < 2; ++h) {
            const int tok = tok0 + w * 32 + nt * 16 + m_;
            const int k0 = h * 32 + qc * 8;
            float4 a = make_float4(0.f, 0.f, 0.f, 0.f), b = a;
            if (tok < N_TOK) {
                a = *(const float4*)(e + tok * 64 + k0);
                b = *(const float4*)(e + tok * 64 + k0 + 4);
            }
            xb[nt][h] = mk_frag(a, b);
        }

    const unsigned short* Wq = wqkv_s + l * 12288;
    {
        f32x4 acc[12][2];
        #pragma unroll
        for (int ft = 0; ft < 12; ++ft) {
            const bf16x8 wa0 = *(const bf16x8*)(Wq + (ft * 2 + 0) * 512 + lane * 8);
            const bf16x8 wa1 = *(const bf16x8*)(Wq + (ft * 2 + 1) * 512 + lane * 8);
            const float4 bv = *(const float4*)(tinb + l * 192 + ft * 16 + qc * 4);
            f32x4 c0; c0[0] = bv.x; c0[1] = bv.y; c0[2] = bv.z; c0[3] = bv.w;
            f32x4 c1 = c0;
            c0 = MFMA_B16(wa0, xb[0][0], c0); c0 = MFMA_B16(wa1, xb[0][1], c0);
            c1 = MFMA_B16(wa0, xb[1][0], c1); c1 = MFMA_B16(wa1, xb[1][1], c1);
            acc[ft][0] = c0; acc[ft][1] = c1;
        }
        #pragma unroll
        for (int ft = 0; ft < 8; ++ft)
            #pragma unroll
            for (int nt = 0; nt < 2; ++nt) {
                const int addr = (nt * 16 + m_) * 136 + ft * 16 + qc * 4;
                *(uint2*)&QKw[addr] = make_uint2(pack2bf(acc[ft][nt][0], acc[ft][nt][1]),
                                                 pack2bf(acc[ft][nt][2], acc[ft][nt][3]));
            }
        #pragma unroll
        for (int ft = 8; ft < 12; ++ft)
            #pragma unroll
            for (int nt = 0; nt < 2; ++nt) {
                const int addr = (nt * 16 + m_) * 72 + (ft - 8) * 16 + qc * 4;
                *(uint2*)&Vw[addr] = make_uint2(pack2bf(acc[ft][nt][0], acc[ft][nt][1]),
                                                pack2bf(acc[ft][nt][2], acc[ft][nt][3]));
            }
    }

    {
        const int node = lane >> 3, head = lane & 7;
        float kk[4][8], vv[4][8], qv[4][8];
        #pragma unroll
        for (int j2 = 0; j2 < 4; ++j2) {
            const bf16x8 kr = *(const bf16x8*)&QKw[(node * 4 + j2) * 136 + 64 + head * 8];
            const bf16x8 vr = *(const bf16x8*)&Vw[(node * 4 + j2) * 72 + head * 8];
            const bf16x8 qr = *(const bf16x8*)&QKw[(node * 4 + j2) * 136 + head * 8];
            #pragma unroll
            for (int d = 0; d < 8; ++d) {
                kk[j2][d] = bf2f(kr[d]); vv[j2][d] = bf2f(vr[d]); qv[j2][d] = bf2f(qr[d]);
            }
        }
        const float scale = 0.35355339059327373f;   // 1/sqrt(8)
        const int nt2 = node >> 2, hq = head >> 2, qq = head & 3;
        #pragma unroll
        for (int i = 0; i < 4; ++i) {
            float s[4];
            #pragma unroll
            for (int j2 = 0; j2 < 4; ++j2) {
                float a2 = 0.f;
                #pragma unroll
                for (int d = 0; d < 8; ++d) a2 += qv[i][d] * kk[j2][d];
                s[j2] = a2 * scale;
            }
            const float mx = fmaxf(fmaxf(s[0], s[1]), fmaxf(s[2], s[3]));
            float p[4], sum = 0.f;
            #pragma unroll
            for (int j2 = 0; j2 < 4; ++j2) { p[j2] = __expf(s[j2] - mx); sum += p[j2]; }
            const float inv = 1.f / sum;
            float o[8];
            #pragma unroll
            for (int d = 0; d < 8; ++d)
                o[d] = (p[0] * vv[0][d] + p[1] * vv[1][d] + p[2] * vv[2][d] + p[3] * vv[3][d]) * inv;
            const int n = (node & 3) * 4 + i;
            *(uint4*)&QKw[(nt2 * 2 + hq) * 512 + qq * 128 + n * 8] =
                make_uint4(pack2bf(o[0], o[1]), pack2bf(o[2], o[3]),
                           pack2bf(o[4], o[5]), pack2bf(o[6], o[7]));
        }
    }

    bf16x8 ob[2][2];
    #pragma unroll
    for (int nt = 0; nt < 2; ++nt)
        #pragma unroll
        for (int h = 0; h < 2; ++h)
            ob[nt][h] = *(const bf16x8*)&QKw[(nt * 2 + h) * 512 + lane * 8];
    const unsigned short* Tw = tow_s + l * 4096;
    f32x4 acc2[4][2] = {};
    #pragma unroll
    for (int ot = 0; ot < 4; ++ot) {
        const bf16x8 t0 = *(const bf16x8*)(Tw + (ot * 2 + 0) * 512 + lane * 8);
        const bf16x8 t1 = *(const bf16x8*)(Tw + (ot * 2 + 1) * 512 + lane * 8);
        acc2[ot][0] = MFMA_B16(t0, ob[0][0], acc2[ot][0]);
        acc2[ot][0] = MFMA_B16(t1, ob[0][1], acc2[ot][0]);
        acc2[ot][1] = MFMA_B16(t0, ob[1][0], acc2[ot][1]);
        acc2[ot][1] = MFMA_B16(t1, ob[1][1], acc2[ot][1]);
    }

    // ---- LN1 → resid registers (no global write) ----
    float resid[2][4][4];       // [nt][ot][r]
    {
        float4 tbv[4], gv[4], bv2[4];
        #pragma unroll
        for (int ot = 0; ot < 4; ++ot) {
            const int o = l * 64 + ot * 16 + qc * 4;
            tbv[ot] = *(const float4*)(tob + o);
            gv[ot]  = *(const float4*)(ln1g + o);
            bv2[ot] = *(const float4*)(ln1b + o);
        }
        #pragma unroll
        for (int nt = 0; nt < 2; ++nt) {
            const int tok = tok0 + w * 32 + nt * 16 + m_;
            const bool valid = tok < N_TOK;
            float v[4][4];
            float s = 0.f;
            #pragma unroll
            for (int ot = 0; ot < 4; ++ot) {
                float4 rs = make_float4(0.f, 0.f, 0.f, 0.f);
                if (valid) rs = *(const float4*)(e + tok * 64 + ot * 16 + qc * 4);
                v[ot][0] = acc2[ot][nt][0] + tbv[ot].x + rs.x;
                v[ot][1] = acc2[ot][nt][1] + tbv[ot].y + rs.y;
                v[ot][2] = acc2[ot][nt][2] + tbv[ot].z + rs.z;
                v[ot][3] = acc2[ot][nt][3] + tbv[ot].w + rs.w;
                s += v[ot][0] + v[ot][1] + v[ot][2] + v[ot][3];
            }
            s += __shfl_xor(s, 16); s += __shfl_xor(s, 32);
            const float mean = s * (1.f / 64.f);
            float vs = 0.f;
            #pragma unroll
            for (int ot = 0; ot < 4; ++ot)
                #pragma unroll
                for (int r = 0; r < 4; ++r) { v[ot][r] -= mean; vs += v[ot][r] * v[ot][r]; }
            vs += __shfl_xor(vs, 16); vs += __shfl_xor(vs, 32);
            const float rr = rsqrtf(vs * (1.f / 64.f) + LN_EPS);
            #pragma unroll
            for (int ot = 0; ot < 4; ++ot) {
                resid[nt][ot][0] = v[ot][0] * rr * gv[ot].x + bv2[ot].x;
                resid[nt][ot][1] = v[ot][1] * rr * gv[ot].y + bv2[ot].y;
                resid[nt][ot][2] = v[ot][2] * rr * gv[ot].z + bv2[ot].z;
                resid[nt][ot][3] = v[ot][3] * rr * gv[ot].w + bv2[ot].w;
            }
        }
    }

    // ================= phase switch: QK/V dead, reuse LDS as Wb | Act =================
    __syncthreads();
    short* Wb = U;                       // [0, 8192)
    short* Aw = &U[8192 + w * 2048];     // [8192, 16384)

    // write LN1 output as bf16 B-frags (same mapping as FFN act store), read back xb
    #pragma unroll
    for (int nt = 0; nt < 2; ++nt)
        #pragma unroll
        for (int ot = 0; ot < 4; ++ot) {
            const int ha = ot >> 1, qa = (ot & 1) * 2 + (qc >> 1), jo = (qc & 1) * 4;
            *(uint2*)&Aw[(nt * 2 + ha) * 512 + qa * 128 + m_ * 8 + jo] =
                make_uint2(pack2bf(resid[nt][ot][0], resid[nt][ot][1]),
                           pack2bf(resid[nt][ot][2], resid[nt][ot][3]));
        }
    bf16x8 xb2[2][2];
    #pragma unroll
    for (int nt = 0; nt < 2; ++nt)
        #pragma unroll
        for (int h = 0; h < 2; ++h)
            xb2[nt][h] = *(const bf16x8*)&Aw[(nt * 2 + h) * 512 + lane * 8];

    // ================= FFN =================
    const uint4* gw1 = (const uint4*)(w1s + l * 131072);
    const uint4* gw2 = (const uint4*)(w2s + l * 131072);
    uint4 p0 = gw1[t], p1 = gw1[t + 256], p2 = gw2[t], p3 = gw2[t + 256];
    *(uint4*)&Wb[t * 8] = p0;            *(uint4*)&Wb[(t + 256) * 8] = p1;
    *(uint4*)&Wb[4096 + t * 8] = p2;     *(uint4*)&Wb[4096 + (t + 256) * 8] = p3;

    f32x4 acc[4][2] = {};

    for (int c = 0; c < 32; ++c) {
        __syncthreads();            // Wb chunk-c visible
        if (c < 31) {               // issue next chunk's global loads (in flight across compute)
            p0 = gw1[(c + 1) * 512 + t];       p1 = gw1[(c + 1) * 512 + t + 256];
            p2 = gw2[(c + 1) * 512 + t];       p3 = gw2[(c + 1) * 512 + t + 256];
        }
        #pragma unroll
        for (int ft = 0; ft < 4; ++ft) {
            const bf16x8 wa0 = *(const bf16x8*)&Wb[(ft * 2 + 0) * 512 + lane * 8];
            const bf16x8 wa1 = *(const bf16x8*)&Wb[(ft * 2 + 1) * 512 + lane * 8];
            const float4 bv = *(const float4*)(ff1b + l * 2048 + c * 64 + ft * 16 + qc * 4);
            f32x4 c0; c0[0] = bv.x; c0[1] = bv.y; c0[2] = bv.z; c0[3] = bv.w;
            f32x4 c1 = c0;
            c0 = MFMA_B16(wa0, xb2[0][0], c0); c0 = MFMA_B16(wa1, xb2[0][1], c0);
            c1 = MFMA_B16(wa0, xb2[1][0], c1); c1 = MFMA_B16(wa1, xb2[1][1], c1);
            const int ha = ft >> 1, qa = (ft & 1) * 2 + (qc >> 1), jo = (qc & 1) * 4;
            const int boff = ha * 512 + qa * 128 + m_ * 8 + jo;
            *(uint2*)&Aw[boff] =
                make_uint2(pack2bf(fmaxf(c0[0], 0.f), fmaxf(c0[1], 0.f)),
                           pack2bf(fmaxf(c0[2], 0.f), fmaxf(c0[3], 0.f)));
            *(uint2*)&Aw[boff + 1024] =
                make_uint2(pack2bf(fmaxf(c1[0], 0.f), fmaxf(c1[1], 0.f)),
                           pack2bf(fmaxf(c1[2], 0.f), fmaxf(c1[3], 0.f)));
        }
        bf16x8 ab[2][2];
        #pragma unroll
        for (int nt = 0; nt < 2; ++nt)
            #pragma unroll
            for (int h = 0; h < 2; ++h)
                ab[nt][h] = *(const bf16x8*)&Aw[(nt * 2 + h) * 512 + lane * 8];
        #pragma unroll
        for (int ot = 0; ot < 4; ++ot) {
            const bf16x8 w20 = *(const bf16x8*)&Wb[4096 + (ot * 2 + 0) * 512 + lane * 8];
            const bf16x8 w21 = *(const bf16x8*)&Wb[4096 + (ot * 2 + 1) * 512 + lane * 8];
            acc[ot][0] = MFMA_B16(w20, ab[0][0], acc[ot][0]);
            acc[ot][0] = MFMA_B16(w21, ab[0][1], acc[ot][0]);
            acc[ot][1] = MFMA_B16(w20, ab[1][0], acc[ot][1]);
            acc[ot][1] = MFMA_B16(w21, ab[1][1], acc[ot][1]);
        }
        __syncthreads();            // all reads of Wb chunk-c done
        if (c < 31) {
            *(uint4*)&Wb[t * 8] = p0;            *(uint4*)&Wb[(t + 256) * 8] = p1;
            *(uint4*)&Wb[4096 + t * 8] = p2;     *(uint4*)&Wb[4096 + (t + 256) * 8] = p3;
        }
    }

    // ---- epilogue: + ff2b + residual (regs), LN2, store ----
    float4 fb2v[4], gv[4], bv2[4];
    #pragma unroll
    for (int ot = 0; ot < 4; ++ot) {
        const int o = l * 64 + ot * 16 + qc * 4;
        fb2v[ot] = *(const float4*)(ff2b + o);
        gv[ot]   = *(const float4*)(ln2g + o);
        bv2[ot]  = *(const float4*)(ln2b + o);
    }
    #pragma unroll
    for (int nt = 0; nt < 2; ++nt) {
        const int tok = tok0 + w * 32 + nt * 16 + m_;
        const bool valid = tok < N_TOK;
        float v[4][4];
        float s = 0.f;
        #pragma unroll
        for (int ot = 0; ot < 4; ++ot) {
            v[ot][0] = acc[ot][nt][0] + fb2v[ot].x + resid[nt][ot][0];
            v[ot][1] = acc[ot][nt][1] + fb2v[ot].y + resid[nt][ot][1];
            v[ot][2] = acc[ot][nt][2] + fb2v[ot].z + resid[nt][ot][2];
            v[ot][3] = acc[ot][nt][3] + fb2v[ot].w + resid[nt][ot][3];
            s += v[ot][0] + v[ot][1] + v[ot][2] + v[ot][3];
        }
        s += __shfl_xor(s, 16); s += __shfl_xor(s, 32);
        const float mean = s * (1.f / 64.f);
        float vs = 0.f;
        #pragma unroll
        for (int ot = 0; ot < 4; ++ot)
            #pragma unroll
            for (int r = 0; r < 4; ++r) { v[ot][r] -= mean; vs += v[ot][r] * v[ot][r]; }
        vs += __shfl_xor(vs, 16); vs += __shfl_xor(vs, 32);
        const float rr = rsqrtf(vs * (1.f / 64.f) + LN_EPS);
        if (valid) {
            #pragma unroll
            for (int ot = 0; ot < 4; ++ot) {
                float4 o4 = make_float4(v[ot][0] * rr * gv[ot].x + bv2[ot].x,
                                        v[ot][1] * rr * gv[ot].y + bv2[ot].y,
                                        v[ot][2] * rr * gv[ot].z + bv2[ot].z,
                                        v[ot][3] * rr * gv[ot].w + bv2[ot].w);
                *(float4*)(eout + tok * 64 + ot * 16 + qc * 4) = o4;
            }
        }
    }
}

// ===================== mean-pool + 2-layer regressor =====================
__global__ __launch_bounds__(256) void k_reg(
    const float* __restrict__ e,
    const float* __restrict__ r1w, const float* __restrict__ r1b,
    const float* __restrict__ r2w, const float* __restrict__ r2b,
    float* __restrict__ out)
{
    __shared__ float r1T[64][64];
    __shared__ float pld[4][64];
    const int t = threadIdx.x;
    #pragma unroll
    for (int i = 0; i < 4; ++i) {
        const int j  = (t & 15) + 16 * i;
        const int kq = t >> 4;
        const float4 v = *(const float4*)(r1w + j * 64 + kq * 4);
        r1T[kq * 4 + 0][j] = v.x; r1T[kq * 4 + 1][j] = v.y;
        r1T[kq * 4 + 2][j] = v.z; r1T[kq * 4 + 3][j] = v.w;
    }
    const int w = t >> 6, lane = t & 63;
    const int n = blockIdx.x * 4 + w;
    const float p = 0.25f * (e[(n * 4 + 0) * 64 + lane] + e[(n * 4 + 1) * 64 + lane] +
                             e[(n * 4 + 2) * 64 + lane] + e[(n * 4 + 3) * 64 + lane]);
    pld[w][lane] = p;
    __syncthreads();
    float acc = r1b[lane];
    #pragma unroll 8
    for (int k = 0; k < 64; ++k) acc += pld[w][k] * r1T[k][lane];
    acc = fmaxf(acc, 0.f);
    float partial = acc * r2w[lane];
    partial += __shfl_xor(partial, 1);  partial += __shfl_xor(partial, 2);
    partial += __shfl_xor(partial, 4);  partial += __shfl_xor(partial, 8);
    partial += __shfl_xor(partial, 16); partial += __shfl_xor(partial, 32);
    if (lane == 0) out[n] = partial + r2b[0];
}

// ===================== host launcher =====================
extern "C" void kernel_launch(void* const* d_in, const int* in_sizes, int n_in,
                              void* d_out, int out_size, void* d_ws, size_t ws_size,
                              hipStream_t stream) {
    const float* x    = (const float*)d_in[0];
    const int*   ei   = (const int*)d_in[1];
    const float* mpw  = (const float*)d_in[2];
    const float* W0   = (const float*)d_in[3];
    const float* b0   = (const float*)d_in[4];
    const float* Wl   = (const float*)d_in[5];
    const float* bl   = (const float*)d_in[6];
    const float* W1   = (const float*)d_in[7];
    const float* b1   = (const float*)d_in[8];
    const float* Wo   = (const float*)d_in[9];
    const float* bo   = (const float*)d_in[10];
    const float* tinw = (const float*)d_in[11];
    const float* tinb = (const float*)d_in[12];
    const float* tow  = (const float*)d_in[13];
    const float* tob  = (const float*)d_in[14];
    const float* ln1g = (const float*)d_in[15];
    const float* ln1b = (const float*)d_in[16];
    const float* ff1w = (const float*)d_in[17];
    const float* ff1b = (const float*)d_in[18];
    const float* ff2w = (const float*)d_in[19];
    const float* ff2b = (const float*)d_in[20];
    const float* ln2g = (const float*)d_in[21];
    const float* ln2b = (const float*)d_in[22];
    const float* r1w  = (const float*)d_in[23];
    const float* r1b  = (const float*)d_in[24];
    const float* r2w  = (const float*)d_in[25];
    const float* r2b  = (const float*)d_in[26];

    const size_t CH = (size_t)M_P * N_NODES * 64;
    float* y    = (float*)d_ws;           // region kept float-sized; bf16 y uses first half
    float* zz   = y + CH;
    float* aggh = zz + CH;
    float* e    = aggh + CH;
    unsigned short* ybf = (unsigned short*)y;
    unsigned short* zbf = (unsigned short*)zz;
    // y region is dead after k_gather — transformer weight scratch (written by k_emb_ws)
    unsigned short* w1s    = (unsigned short*)y;
    unsigned short* w2s    = w1s + 262144;
    unsigned short* wqkv_s = w2s + 262144;
    unsigned short* tow_s  = wqkv_s + 24576;
    // e region is dead until k_emb_ws — bins (7.68MB) + overflow list
    unsigned short* bins = (unsigned short*)e;
    int* ovf_cnt = (int*)((char*)e + (size_t)N_ROWS * 64);
    int2* ovf    = (int2*)((char*)ovf_cnt + 16);

    hipMemsetAsync(bins, 0, (size_t)N_ROWS * 64 + 16, stream);  // headers + ovf_cnt
    k_phaseA<<<NB_FILL + NB_LIN, 256, 0, stream>>>(ei, bins, ovf_cnt, ovf,
                                                   x, Wl, W0, W1, b0, bl, b1, ybf, zbf);
    k_gather<<<N_ROWS / 4, 256, 0, stream>>>(bins, ovf_cnt, ovf, ybf, aggh);
    k_emb_ws<<<N_NODES / 16 + 1024, 256, 0, stream>>>(aggh, zbf, Wo, bo, mpw, e,
                                                      ff1w, ff2w, tinw, tow,
                                                      w1s, w2s, wqkv_s, tow_s);
    for (int l = 0; l < 2; ++l) {
        k_layer<<<(N_TOK + 127) / 128, 256, 0, stream>>>(e, wqkv_s, tinb, tow_s, tob,
                                                         ln1g, ln1b, w1s, w2s, ff1b, ff2b,
                                                         ln2g, ln2b, e, l);
    }
    k_reg<<<N_NODES / 4, 256, 0, stream>>>(e, r1w, r1b, r2w, r2b, (float*)d_out);
}

// Round 15
// 572.637 us; speedup vs baseline: 1.0103x; 1.0103x over previous
//
#include <hip/hip_runtime.h>
#include <hip/hip_bf16.h>
#include <math.h>

#define N_NODES 30000
#define M_P     4
#define E_EDGES 480000
#define N_TOK   (N_NODES * 4)
#define N_ROWS  (M_P * N_NODES)      // 120000 (m,src) rows
#define SLOTS   30                   // per-row bin slots; row = 64B: [int cnt | 30 ushort]
#define OVF_CAP 65536                // overflow list capacity (never used in practice)
#define LN_EPS  1e-5f

#define NB_FILL 1875                 // fill blocks (M*E / 1024)
#define NB_LIN  1876                 // lin blocks (469 x 4; each does which=0 and 1)

typedef short bf16x8 __attribute__((ext_vector_type(8)));
typedef float f32x4  __attribute__((ext_vector_type(4)));
#define MFMA_B16(a, b, c) __builtin_amdgcn_mfma_f32_16x16x32_bf16(a, b, c, 0, 0, 0)

__device__ inline unsigned short f2bf(float f) {
    union { float f; unsigned u; } v; v.f = f;
    unsigned r = v.u + 0x7fffu + ((v.u >> 16) & 1u);
    return (unsigned short)(r >> 16);
}
// HW packed cvt (v_cvt_pk_bf16_f32, RNE — same rounding as f2bf)
__device__ inline unsigned pack2bf(float a, float b) {
    union { __hip_bfloat162 h; unsigned u; } cv;
    cv.h = __float22bfloat162_rn(make_float2(a, b));
    return cv.u;
}
__device__ inline float bf2f(short s) {
    union { unsigned u; float f; } v; v.u = ((unsigned)(unsigned short)s) << 16;
    return v.f;
}
// Build a B-fragment (8 contiguous k-elements of one token) directly from two float4s
__device__ inline bf16x8 mk_frag(const float4& a, const float4& b) {
    union { uint4 u; bf16x8 v; } cv;
    cv.u = make_uint4(pack2bf(a.x, a.y), pack2bf(a.z, a.w),
                      pack2bf(b.x, b.y), pack2bf(b.z, b.w));
    return cv.v;
}

// ===================== Phase A mega-kernel: fill (critical path, first) + lin MFMA =====================
// lin blocks now produce BOTH y and z for one m: x frags read once, weight LDS (16 KB) reused
// sequentially for the two weight sets — halves lin's x fetch and block count.
__global__ __launch_bounds__(256) void k_phaseA(
    const int* __restrict__ ei, unsigned short* __restrict__ bins,
    int* __restrict__ ovf_cnt, int2* __restrict__ ovf,
    const float* __restrict__ x,
    const float* __restrict__ Wl, const float* __restrict__ W0, const float* __restrict__ W1,
    const float* __restrict__ b0, const float* __restrict__ bl, const float* __restrict__ b1,
    unsigned short* __restrict__ ybf, unsigned short* __restrict__ zbf)
{
    __shared__ __align__(16) short Wf[8192];    // 16 KB weight frags (lin blocks only)
    const int bid = blockIdx.x;
    const int t = threadIdx.x;

    if (bid < NB_FILL) {
        // ---------------- fill: 4 edges/thread ----------------
        const int base = bid * 1024 + t;
        int rows[4], dsts[4];
        #pragma unroll
        for (int i = 0; i < 4; ++i) {
            const int g = base + i * 256;               // coalesced per i
            const int m = g / E_EDGES;
            const int e = g - m * E_EDGES;
            rows[i] = m * N_NODES + ei[(m * 2) * E_EDGES + e];
            dsts[i] = ei[(m * 2 + 1) * E_EDGES + e];
        }
        int pos[4];
        #pragma unroll
        for (int i = 0; i < 4; ++i)
            pos[i] = atomicAdd((int*)bins + rows[i] * 16, 1);   // header int of the 64B bin
        #pragma unroll
        for (int i = 0; i < 4; ++i) {
            if (pos[i] < SLOTS) {
                bins[rows[i] * 32 + 2 + pos[i]] = (unsigned short)dsts[i];
            } else {                                    // statistically never taken
                const int ix = atomicAdd(ovf_cnt, 1);
                if (ix < OVF_CAP) ovf[ix] = make_int2(rows[i], dsts[i]);
            }
        }
    } else {
        // ---------------- lin: y = x@Wl^T and z = x@(W0+W1)^T + biases (bf16 out) ----------------
        const int lid = bid - NB_FILL;
        const int bx = lid % 469;
        const int m  = lid / 469;                       // 0..3
        const int w = t >> 6, lane = t & 63;
        const int m_ = lane & 15, qc = lane >> 4;
        const int node = bx * 64 + w * 16 + m_;

        // x B-frags once, shared by both GEMMs
        bf16x8 xb[4];
        #pragma unroll
        for (int hh = 0; hh < 4; ++hh) {
            float4 a = make_float4(0.f, 0.f, 0.f, 0.f), b = a;
            if (node < N_NODES) {
                a = *(const float4*)(x + node * 128 + hh * 32 + qc * 8);
                b = *(const float4*)(x + node * 128 + hh * 32 + qc * 8 + 4);
            }
            xb[hh] = mk_frag(a, b);
        }

        for (int which = 0; which < 2; ++which) {
            __syncthreads();                            // Wf free for (re)staging
            #pragma unroll
            for (int i = 0; i < 32; ++i) {
                const int d = t + 256 * i;              // [0, 8192)
                const int fg = d >> 9, rem = d & 511;
                const int qmm = rem >> 3, j = d & 7;
                const int q = qmm >> 4, mm = qmm & 15;
                const int ot = fg >> 2, hh = fg & 3;
                const int row = ot * 16 + mm, k = hh * 32 + q * 8 + j;
                float v;
                if (which == 0) v = Wl[(m * 64 + row) * 128 + k];
                else            v = W0[(m * 64 + row) * 128 + k] + W1[(m * 64 + row) * 128 + k];
                Wf[d] = (short)f2bf(v);
            }
            __syncthreads();

            f32x4 acc[4];
            #pragma unroll
            for (int ot = 0; ot < 4; ++ot) {
                f32x4 c = {};
                if (which) {
                    const int o = m * 64 + ot * 16 + qc * 4;
                    const float4 v0 = *(const float4*)(b0 + o);
                    const float4 v1 = *(const float4*)(b1 + o);
                    const float4 vl = *(const float4*)(bl + o);
                    c[0] = v0.x + v1.x + vl.x; c[1] = v0.y + v1.y + vl.y;
                    c[2] = v0.z + v1.z + vl.z; c[3] = v0.w + v1.w + vl.w;
                }
                #pragma unroll
                for (int hh = 0; hh < 4; ++hh) {
                    const bf16x8 wa = *(const bf16x8*)&Wf[(ot * 4 + hh) * 512 + lane * 8];
                    c = MFMA_B16(wa, xb[hh], c);
                }
                acc[ot] = c;
            }
            unsigned short* outp = which ? zbf : ybf;
            if (node < N_NODES) {
                #pragma unroll
                for (int ot = 0; ot < 4; ++ot) {
                    uint2 pk = make_uint2(pack2bf(acc[ot][0], acc[ot][1]),
                                          pack2bf(acc[ot][2], acc[ot][3]));
                    *(uint2*)(outp + ((size_t)m * N_NODES + node) * 64 + ot * 16 + qc * 4) = pk;
                }
            }
        }
    }
}

// ===================== Gather-reduce — one wave per (m,src) row; 4-way ILP; bf16 y =====================
__global__ __launch_bounds__(256) void k_gather(
    const unsigned short* __restrict__ bins,
    const int* __restrict__ ovf_cnt, const int2* __restrict__ ovf,
    const unsigned short* __restrict__ ybf, float* __restrict__ aggh)
{
    const int w = threadIdx.x >> 6, lane = threadIdx.x & 63;
    const int row = blockIdx.x * 4 + w;                 // < N_ROWS
    const int m = row / N_NODES;
    const unsigned short* ym = ybf + (size_t)m * N_NODES * 64;
    const int v = (lane < 32) ? bins[row * 32 + lane] : 0;  // lanes 0,1 = header halves
    const int v0 = __shfl(v, 0), v1 = __shfl(v, 1);
    const int tot = (v0 & 0xffff) | (v1 << 16);
    const int cnt = min(tot, SLOTS);
    float a0 = 0.f, a1 = 0.f, a2 = 0.f, a3 = 0.f;
    int j = 0;
    for (; j + 4 <= cnt; j += 4) {
        const int r0 = __shfl(v, j + 2), r1 = __shfl(v, j + 3);
        const int r2 = __shfl(v, j + 4), r3 = __shfl(v, j + 5);
        a0 += bf2f((short)ym[r0 * 64 + lane]); a1 += bf2f((short)ym[r1 * 64 + lane]);
        a2 += bf2f((short)ym[r2 * 64 + lane]); a3 += bf2f((short)ym[r3 * 64 + lane]);
    }
    for (; j < cnt; ++j) {
        const int r = __shfl(v, j + 2);
        a0 += bf2f((short)ym[r * 64 + lane]);
    }
    if (tot > SLOTS) {                                  // statistically never taken
        const int no = min(*ovf_cnt, OVF_CAP);
        for (int i2 = 0; i2 < no; ++i2) {
            const int2 ent = ovf[i2];
            if (ent.x == row) a0 += bf2f((short)ym[ent.y * 64 + lane]);
        }
    }
    aggh[(size_t)row * 64 + lane] = (a0 + a1) + (a2 + a3);
}

// ===================== emb + transformer weight shuffle (merged; y region dead by now) ==========
__global__ __launch_bounds__(256) void k_emb_ws(
    const float* __restrict__ aggh, const unsigned short* __restrict__ zbf,
    const float* __restrict__ Wo, const float* __restrict__ bo,
    const float* __restrict__ mpw, float* __restrict__ e,
    const float* __restrict__ ff1w, const float* __restrict__ ff2w,
    const float* __restrict__ tinw, const float* __restrict__ tow,
    unsigned short* __restrict__ w1s, unsigned short* __restrict__ w2s,
    unsigned short* __restrict__ wqkv_s, unsigned short* __restrict__ tow_s)
{
    __shared__ float hT[64][20];
    __shared__ float WoT[64][64];
    const int t = threadIdx.x;
    const int bid = blockIdx.x;

    if (bid >= N_NODES / 16) {
        const int g = (bid - N_NODES / 16) * 256 + t;   // [0, 262144)
        {
            const int l = g >> 17, r2 = g & 131071;
            const int f = r2 >> 6, k = r2 & 63;
            const int c = f >> 6, fc = f & 63, ft = fc >> 4, m = fc & 15;
            const int h = k >> 5, q = (k >> 3) & 3, j = k & 7;
            w1s[l * 131072 + c * 4096 + (ft * 2 + h) * 512 + (q * 16 + m) * 8 + j] = f2bf(ff1w[g]);
        }
        {
            const int l = g >> 17, r2 = g & 131071;
            const int o = r2 >> 11, f = r2 & 2047;
            const int c = f >> 6, fc = f & 63, h = fc >> 5, q = (fc >> 3) & 3, j = fc & 7;
            const int ot = o >> 4, m = o & 15;
            w2s[l * 131072 + c * 4096 + (ot * 2 + h) * 512 + (q * 16 + m) * 8 + j] = f2bf(ff2w[g]);
        }
        if (g < 2 * 192 * 64) {
            const int l = g / 12288, r2 = g - l * 12288;
            const int f = r2 >> 6, k = r2 & 63;
            const int ft = f >> 4, m = f & 15;
            const int h = k >> 5, q = (k >> 3) & 3, j = k & 7;
            wqkv_s[l * 12288 + (ft * 2 + h) * 512 + (q * 16 + m) * 8 + j] = f2bf(tinw[g]);
        }
        if (g < 2 * 64 * 64) {
            const int l = g >> 12, r2 = g & 4095;
            const int o = r2 >> 6, k = r2 & 63;
            const int ot = o >> 4, m = o & 15;
            const int h = k >> 5, q = (k >> 3) & 3, j = k & 7;
            tow_s[l * 4096 + (ot * 2 + h) * 512 + (q * 16 + m) * 8 + j] = f2bf(tow[g]);
        }
        return;
    }

    const int node0 = bid * 16;
    for (int m = 0; m < 4; ++m) {
        #pragma unroll
        for (int i = 0; i < 4; ++i) {
            const int o  = (t & 15) + 16 * i;
            const int kq = t >> 4;
            const float4 v = *(const float4*)(Wo + (m * 64 + o) * 64 + kq * 4);
            WoT[kq * 4 + 0][o] = v.x; WoT[kq * 4 + 1][o] = v.y;
            WoT[kq * 4 + 2][o] = v.z; WoT[kq * 4 + 3][o] = v.w;
        }
        {
            const int node = t & 15, kq = t >> 4;
            const int n = node0 + node;
            const float4 a = *(const float4*)(aggh + ((size_t)m * N_NODES + n) * 64 + kq * 4);
            const uint2 bz = *(const uint2*)(zbf + ((size_t)m * N_NODES + n) * 64 + kq * 4);
            hT[kq * 4 + 0][node] = fmaxf(a.x + bf2f((short)(bz.x & 0xffff)), 0.f);
            hT[kq * 4 + 1][node] = fmaxf(a.y + bf2f((short)(bz.x >> 16)), 0.f);
            hT[kq * 4 + 2][node] = fmaxf(a.z + bf2f((short)(bz.y & 0xffff)), 0.f);
            hT[kq * 4 + 3][node] = fmaxf(a.w + bf2f((short)(bz.y >> 16)), 0.f);
        }
        __syncthreads();
        const int o = t & 63, nl4 = (t >> 6) * 4;
        float acc[4] = {};
        #pragma unroll 8
        for (int k = 0; k < 64; ++k) {
            const float bw = WoT[k][o];
            const float4 a = *(const float4*)&hT[k][nl4];
            acc[0] += a.x * bw; acc[1] += a.y * bw; acc[2] += a.z * bw; acc[3] += a.w * bw;
        }
        const float bb = bo[m * 64 + o];
        const float w  = mpw[m];
        #pragma unroll
        for (int i = 0; i < 4; ++i)
            e[((node0 + nl4 + i) * 4 + m) * 64 + o] = (acc[i] + bb) * w;
        __syncthreads();
    }
}

// ===================== attention via bf16 MFMA — direct-reg X, 52KB LDS, 3 blk/CU ==========
__global__ __launch_bounds__(256, 3) void k_attn_mfma(
    const float* __restrict__ e,
    const unsigned short* __restrict__ wqkv_s, const float* __restrict__ tinb,
    const unsigned short* __restrict__ tow_s, const float* __restrict__ tob,
    const float* __restrict__ ln1g, const float* __restrict__ ln1b,
    float* __restrict__ eout, int l)
{
    __shared__ __align__(16) short QK[17408];    // 34 KB: [w][4352]
    __shared__ __align__(16) short Vb[9216];     // 18 KB: [w][2304]
    const int t = threadIdx.x;
    const int w = t >> 6, lane = t & 63;
    const int m_ = lane & 15, qc = lane >> 4;
    const int tok0 = blockIdx.x * 128;
    short* QKw = &QK[w * 4352];
    short* Vw  = &Vb[w * 2304];

    bf16x8 xb[2][2];
    #pragma unroll
    for (int nt = 0; nt < 2; ++nt)
        #pragma unroll
        for (int h = 0; h < 2; ++h) {
            const int tok = tok0 + w * 32 + nt * 16 + m_;
            const int k0 = h * 32 + qc * 8;
            float4 a = make_float4(0.f, 0.f, 0.f, 0.f), b = a;
            if (tok < N_TOK) {
                a = *(const float4*)(e + tok * 64 + k0);
                b = *(const float4*)(e + tok * 64 + k0 + 4);
            }
            xb[nt][h] = mk_frag(a, b);
        }

    const unsigned short* Wq = wqkv_s + l * 12288;
    f32x4 acc[12][2];
    #pragma unroll
    for (int ft = 0; ft < 12; ++ft) {
        const bf16x8 wa0 = *(const bf16x8*)(Wq + (ft * 2 + 0) * 512 + lane * 8);
        const bf16x8 wa1 = *(const bf16x8*)(Wq + (ft * 2 + 1) * 512 + lane * 8);
        const float4 bv = *(const float4*)(tinb + l * 192 + ft * 16 + qc * 4);
        f32x4 c0; c0[0] = bv.x; c0[1] = bv.y; c0[2] = bv.z; c0[3] = bv.w;
        f32x4 c1 = c0;
        c0 = MFMA_B16(wa0, xb[0][0], c0); c0 = MFMA_B16(wa1, xb[0][1], c0);
        c1 = MFMA_B16(wa0, xb[1][0], c1); c1 = MFMA_B16(wa1, xb[1][1], c1);
        acc[ft][0] = c0; acc[ft][1] = c1;
    }
    #pragma unroll
    for (int ft = 0; ft < 8; ++ft)
        #pragma unroll
        for (int nt = 0; nt < 2; ++nt) {
            const int addr = (nt * 16 + m_) * 136 + ft * 16 + qc * 4;
            *(uint2*)&QKw[addr] = make_uint2(pack2bf(acc[ft][nt][0], acc[ft][nt][1]),
                                             pack2bf(acc[ft][nt][2], acc[ft][nt][3]));
        }
    #pragma unroll
    for (int ft = 8; ft < 12; ++ft)
        #pragma unroll
        for (int nt = 0; nt < 2; ++nt) {
            const int addr = (nt * 16 + m_) * 72 + (ft - 8) * 16 + qc * 4;
            *(uint2*)&Vw[addr] = make_uint2(pack2bf(acc[ft][nt][0], acc[ft][nt][1]),
                                            pack2bf(acc[ft][nt][2], acc[ft][nt][3]));
        }

    {
        const int node = lane >> 3, head = lane & 7;
        float kk[4][8], vv[4][8], qv[4][8];
        #pragma unroll
        for (int j2 = 0; j2 < 4; ++j2) {
            const bf16x8 kr = *(const bf16x8*)&QKw[(node * 4 + j2) * 136 + 64 + head * 8];
            const bf16x8 vr = *(const bf16x8*)&Vw[(node * 4 + j2) * 72 + head * 8];
            const bf16x8 qr = *(const bf16x8*)&QKw[(node * 4 + j2) * 136 + head * 8];
            #pragma unroll
            for (int d = 0; d < 8; ++d) {
                kk[j2][d] = bf2f(kr[d]); vv[j2][d] = bf2f(vr[d]); qv[j2][d] = bf2f(qr[d]);
            }
        }
        const float scale = 0.35355339059327373f;   // 1/sqrt(8)
        const int nt2 = node >> 2, hq = head >> 2, qq = head & 3;
        #pragma unroll
        for (int i = 0; i < 4; ++i) {
            float s[4];
            #pragma unroll
            for (int j2 = 0; j2 < 4; ++j2) {
                float a2 = 0.f;
                #pragma unroll
                for (int d = 0; d < 8; ++d) a2 += qv[i][d] * kk[j2][d];
                s[j2] = a2 * scale;
            }
            const float mx = fmaxf(fmaxf(s[0], s[1]), fmaxf(s[2], s[3]));
            float p[4], sum = 0.f;
            #pragma unroll
            for (int j2 = 0; j2 < 4; ++j2) { p[j2] = __expf(s[j2] - mx); sum += p[j2]; }
            const float inv = 1.f / sum;
            float o[8];
            #pragma unroll
            for (int d = 0; d < 8; ++d)
                o[d] = (p[0] * vv[0][d] + p[1] * vv[1][d] + p[2] * vv[2][d] + p[3] * vv[3][d]) * inv;
            const int n = (node & 3) * 4 + i;
            *(uint4*)&QKw[(nt2 * 2 + hq) * 512 + qq * 128 + n * 8] =
                make_uint4(pack2bf(o[0], o[1]), pack2bf(o[2], o[3]),
                           pack2bf(o[4], o[5]), pack2bf(o[6], o[7]));
        }
    }

    bf16x8 ob[2][2];
    #pragma unroll
    for (int nt = 0; nt < 2; ++nt)
        #pragma unroll
        for (int h = 0; h < 2; ++h)
            ob[nt][h] = *(const bf16x8*)&QKw[(nt * 2 + h) * 512 + lane * 8];
    const unsigned short* Tw = tow_s + l * 4096;
    f32x4 acc2[4][2] = {};
    #pragma unroll
    for (int ot = 0; ot < 4; ++ot) {
        const bf16x8 t0 = *(const bf16x8*)(Tw + (ot * 2 + 0) * 512 + lane * 8);
        const bf16x8 t1 = *(const bf16x8*)(Tw + (ot * 2 + 1) * 512 + lane * 8);
        acc2[ot][0] = MFMA_B16(t0, ob[0][0], acc2[ot][0]);
        acc2[ot][0] = MFMA_B16(t1, ob[0][1], acc2[ot][0]);
        acc2[ot][1] = MFMA_B16(t0, ob[1][0], acc2[ot][1]);
        acc2[ot][1] = MFMA_B16(t1, ob[1][1], acc2[ot][1]);
    }

    float4 tbv[4], gv[4], bv2[4];
    #pragma unroll
    for (int ot = 0; ot < 4; ++ot) {
        const int o = l * 64 + ot * 16 + qc * 4;
        tbv[ot] = *(const float4*)(tob + o);
        gv[ot]  = *(const float4*)(ln1g + o);
        bv2[ot] = *(const float4*)(ln1b + o);
    }
    #pragma unroll
    for (int nt = 0; nt < 2; ++nt) {
        const int tok = tok0 + w * 32 + nt * 16 + m_;
        const bool valid = tok < N_TOK;
        float v[4][4];
        float s = 0.f;
        #pragma unroll
        for (int ot = 0; ot < 4; ++ot) {
            float4 rs = make_float4(0.f, 0.f, 0.f, 0.f);
            if (valid) rs = *(const float4*)(e + tok * 64 + ot * 16 + qc * 4);
            v[ot][0] = acc2[ot][nt][0] + tbv[ot].x + rs.x;
            v[ot][1] = acc2[ot][nt][1] + tbv[ot].y + rs.y;
            v[ot][2] = acc2[ot][nt][2] + tbv[ot].z + rs.z;
            v[ot][3] = acc2[ot][nt][3] + tbv[ot].w + rs.w;
            s += v[ot][0] + v[ot][1] + v[ot][2] + v[ot][3];
        }
        s += __shfl_xor(s, 16); s += __shfl_xor(s, 32);
        const float mean = s * (1.f / 64.f);
        float vs = 0.f;
        #pragma unroll
        for (int ot = 0; ot < 4; ++ot)
            #pragma unroll
            for (int r = 0; r < 4; ++r) { v[ot][r] -= mean; vs += v[ot][r] * v[ot][r]; }
        vs += __shfl_xor(vs, 16); vs += __shfl_xor(vs, 32);
        const float rr = rsqrtf(vs * (1.f / 64.f) + LN_EPS);
        if (valid) {
            #pragma unroll
            for (int ot = 0; ot < 4; ++ot) {
                float4 o4 = make_float4(v[ot][0] * rr * gv[ot].x + bv2[ot].x,
                                        v[ot][1] * rr * gv[ot].y + bv2[ot].y,
                                        v[ot][2] * rr * gv[ot].z + bv2[ot].z,
                                        v[ot][3] * rr * gv[ot].w + bv2[ot].w);
                *(float4*)(eout + tok * 64 + ot * 16 + qc * 4) = o4;
            }
        }
    }
}

// ===================== FFN via bf16 MFMA — direct-reg X, Wb prefetch, 32KB LDS, 4 blk/CU ======
__global__ __launch_bounds__(256, 4) void k_ffn_mfma(
    const float* __restrict__ e,
    const unsigned short* __restrict__ w1s, const unsigned short* __restrict__ w2s,
    const float* __restrict__ ff1b, const float* __restrict__ ff2b,
    const float* __restrict__ ln2g, const float* __restrict__ ln2b,
    float* __restrict__ eout, int l)
{
    __shared__ __align__(16) short Act[8192];    // 16 KB [w][2048] (same-wave RAW)
    __shared__ __align__(16) short Wb[8192];     // 16 KB [ W1 4096 | W2 4096 ]
    const int t = threadIdx.x;
    const int w = t >> 6, lane = t & 63;
    const int m_ = lane & 15, qc = lane >> 4;
    const int tok0 = blockIdx.x * 128;
    short* Aw = &Act[w * 2048];

    bf16x8 xb[2][2];
    #pragma unroll
    for (int nt = 0; nt < 2; ++nt)
        #pragma unroll
        for (int h = 0; h < 2; ++h) {
            const int tok = tok0 + w * 32 + nt * 16 + m_;
            const int k0 = h * 32 + qc * 8;
            float4 a = make_float4(0.f, 0.f, 0.f, 0.f), b = a;
            if (tok < N_TOK) {
                a = *(const float4*)(e + tok * 64 + k0);
                b = *(const float4*)(e + tok * 64 + k0 + 4);
            }
            xb[nt][h] = mk_frag(a, b);
        }

    const uint4* gw1 = (const uint4*)(w1s + l * 131072);
    const uint4* gw2 = (const uint4*)(w2s + l * 131072);
    uint4 p0 = gw1[t], p1 = gw1[t + 256], p2 = gw2[t], p3 = gw2[t + 256];
    *(uint4*)&Wb[t * 8] = p0;            *(uint4*)&Wb[(t + 256) * 8] = p1;
    *(uint4*)&Wb[4096 + t * 8] = p2;     *(uint4*)&Wb[4096 + (t + 256) * 8] = p3;

    f32x4 acc[4][2] = {};

    for (int c = 0; c < 32; ++c) {
        __syncthreads();            // Wb chunk-c visible
        if (c < 31) {               // issue next chunk's global loads (in flight across compute)
            p0 = gw1[(c + 1) * 512 + t];       p1 = gw1[(c + 1) * 512 + t + 256];
            p2 = gw2[(c + 1) * 512 + t];       p3 = gw2[(c + 1) * 512 + t + 256];
        }
        #pragma unroll
        for (int ft = 0; ft < 4; ++ft) {
            const bf16x8 wa0 = *(const bf16x8*)&Wb[(ft * 2 + 0) * 512 + lane * 8];
            const bf16x8 wa1 = *(const bf16x8*)&Wb[(ft * 2 + 1) * 512 + lane * 8];
            const float4 bv = *(const float4*)(ff1b + l * 2048 + c * 64 + ft * 16 + qc * 4);
            f32x4 c0; c0[0] = bv.x; c0[1] = bv.y; c0[2] = bv.z; c0[3] = bv.w;
            f32x4 c1 = c0;
            c0 = MFMA_B16(wa0, xb[0][0], c0); c0 = MFMA_B16(wa1, xb[0][1], c0);
            c1 = MFMA_B16(wa0, xb[1][0], c1); c1 = MFMA_B16(wa1, xb[1][1], c1);
            const int ha = ft >> 1, qa = (ft & 1) * 2 + (qc >> 1), jo = (qc & 1) * 4;
            const int boff = ha * 512 + qa * 128 + m_ * 8 + jo;
            *(uint2*)&Aw[boff] =
                make_uint2(pack2bf(fmaxf(c0[0], 0.f), fmaxf(c0[1], 0.f)),
                           pack2bf(fmaxf(c0[2], 0.f), fmaxf(c0[3], 0.f)));
            *(uint2*)&Aw[boff + 1024] =
                make_uint2(pack2bf(fmaxf(c1[0], 0.f), fmaxf(c1[1], 0.f)),
                           pack2bf(fmaxf(c1[2], 0.f), fmaxf(c1[3], 0.f)));
        }
        bf16x8 ab[2][2];
        #pragma unroll
        for (int nt = 0; nt < 2; ++nt)
            #pragma unroll
            for (int h = 0; h < 2; ++h)
                ab[nt][h] = *(const bf16x8*)&Aw[(nt * 2 + h) * 512 + lane * 8];
        #pragma unroll
        for (int ot = 0; ot < 4; ++ot) {
            const bf16x8 w20 = *(const bf16x8*)&Wb[4096 + (ot * 2 + 0) * 512 + lane * 8];
            const bf16x8 w21 = *(const bf16x8*)&Wb[4096 + (ot * 2 + 1) * 512 + lane * 8];
            acc[ot][0] = MFMA_B16(w20, ab[0][0], acc[ot][0]);
            acc[ot][0] = MFMA_B16(w21, ab[0][1], acc[ot][0]);
            acc[ot][1] = MFMA_B16(w20, ab[1][0], acc[ot][1]);
            acc[ot][1] = MFMA_B16(w21, ab[1][1], acc[ot][1]);
        }
        __syncthreads();            // all reads of Wb chunk-c done
        if (c < 31) {
            *(uint4*)&Wb[t * 8] = p0;            *(uint4*)&Wb[(t + 256) * 8] = p1;
            *(uint4*)&Wb[4096 + t * 8] = p2;     *(uint4*)&Wb[4096 + (t + 256) * 8] = p3;
        }
    }

    float4 fb2v[4], gv[4], bv2[4];
    #pragma unroll
    for (int ot = 0; ot < 4; ++ot) {
        const int o = l * 64 + ot * 16 + qc * 4;
        fb2v[ot] = *(const float4*)(ff2b + o);
        gv[ot]   = *(const float4*)(ln2g + o);
        bv2[ot]  = *(const float4*)(ln2b + o);
    }
    #pragma unroll
    for (int nt = 0; nt < 2; ++nt) {
        const int tok = tok0 + w * 32 + nt * 16 + m_;
        const bool valid = tok < N_TOK;
        float v[4][4];
        float s = 0.f;
        #pragma unroll
        for (int ot = 0; ot < 4; ++ot) {
            float4 rs = make_float4(0.f, 0.f, 0.f, 0.f);
            if (valid) rs = *(const float4*)(e + tok * 64 + ot * 16 + qc * 4);
            v[ot][0] = acc[ot][nt][0] + fb2v[ot].x + rs.x;
            v[ot][1] = acc[ot][nt][1] + fb2v[ot].y + rs.y;
            v[ot][2] = acc[ot][nt][2] + fb2v[ot].z + rs.z;
            v[ot][3] = acc[ot][nt][3] + fb2v[ot].w + rs.w;
            s += v[ot][0] + v[ot][1] + v[ot][2] + v[ot][3];
        }
        s += __shfl_xor(s, 16); s += __shfl_xor(s, 32);
        const float mean = s * (1.f / 64.f);
        float vs = 0.f;
        #pragma unroll
        for (int ot = 0; ot < 4; ++ot)
            #pragma unroll
            for (int r = 0; r < 4; ++r) { v[ot][r] -= mean; vs += v[ot][r] * v[ot][r]; }
        vs += __shfl_xor(vs, 16); vs += __shfl_xor(vs, 32);
        const float rr = rsqrtf(vs * (1.f / 64.f) + LN_EPS);
        if (valid) {
            #pragma unroll
            for (int ot = 0; ot < 4; ++ot) {
                float4 o4 = make_float4(v[ot][0] * rr * gv[ot].x + bv2[ot].x,
                                        v[ot][1] * rr * gv[ot].y + bv2[ot].y,
                                        v[ot][2] * rr * gv[ot].z + bv2[ot].z,
                                        v[ot][3] * rr * gv[ot].w + bv2[ot].w);
                *(float4*)(eout + tok * 64 + ot * 16 + qc * 4) = o4;
            }
        }
    }
}

// ===================== mean-pool + 2-layer regressor =====================
__global__ __launch_bounds__(256) void k_reg(
    const float* __restrict__ e,
    const float* __restrict__ r1w, const float* __restrict__ r1b,
    const float* __restrict__ r2w, const float* __restrict__ r2b,
    float* __restrict__ out)
{
    __shared__ float r1T[64][64];
    __shared__ float pld[4][64];
    const int t = threadIdx.x;
    #pragma unroll
    for (int i = 0; i < 4; ++i) {
        const int j  = (t & 15) + 16 * i;
        const int kq = t >> 4;
        const float4 v = *(const float4*)(r1w + j * 64 + kq * 4);
        r1T[kq * 4 + 0][j] = v.x; r1T[kq * 4 + 1][j] = v.y;
        r1T[kq * 4 + 2][j] = v.z; r1T[kq * 4 + 3][j] = v.w;
    }
    const int w = t >> 6, lane = t & 63;
    const int n = blockIdx.x * 4 + w;
    const float p = 0.25f * (e[(n * 4 + 0) * 64 + lane] + e[(n * 4 + 1) * 64 + lane] +
                             e[(n * 4 + 2) * 64 + lane] + e[(n * 4 + 3) * 64 + lane]);
    pld[w][lane] = p;
    __syncthreads();
    float acc = r1b[lane];
    #pragma unroll 8
    for (int k = 0; k < 64; ++k) acc += pld[w][k] * r1T[k][lane];
    acc = fmaxf(acc, 0.f);
    float partial = acc * r2w[lane];
    partial += __shfl_xor(partial, 1);  partial += __shfl_xor(partial, 2);
    partial += __shfl_xor(partial, 4);  partial += __shfl_xor(partial, 8);
    partial += __shfl_xor(partial, 16); partial += __shfl_xor(partial, 32);
    if (lane == 0) out[n] = partial + r2b[0];
}

// ===================== host launcher =====================
extern "C" void kernel_launch(void* const* d_in, const int* in_sizes, int n_in,
                              void* d_out, int out_size, void* d_ws, size_t ws_size,
                              hipStream_t stream) {
    const float* x    = (const float*)d_in[0];
    const int*   ei   = (const int*)d_in[1];
    const float* mpw  = (const float*)d_in[2];
    const float* W0   = (const float*)d_in[3];
    const float* b0   = (const float*)d_in[4];
    const float* Wl   = (const float*)d_in[5];
    const float* bl   = (const float*)d_in[6];
    const float* W1   = (const float*)d_in[7];
    const float* b1   = (const float*)d_in[8];
    const float* Wo   = (const float*)d_in[9];
    const float* bo   = (const float*)d_in[10];
    const float* tinw = (const float*)d_in[11];
    const float* tinb = (const float*)d_in[12];
    const float* tow  = (const float*)d_in[13];
    const float* tob  = (const float*)d_in[14];
    const float* ln1g = (const float*)d_in[15];
    const float* ln1b = (const float*)d_in[16];
    const float* ff1w = (const float*)d_in[17];
    const float* ff1b = (const float*)d_in[18];
    const float* ff2w = (const float*)d_in[19];
    const float* ff2b = (const float*)d_in[20];
    const float* ln2g = (const float*)d_in[21];
    const float* ln2b = (const float*)d_in[22];
    const float* r1w  = (const float*)d_in[23];
    const float* r1b  = (const float*)d_in[24];
    const float* r2w  = (const float*)d_in[25];
    const float* r2b  = (const float*)d_in[26];

    const size_t CH = (size_t)M_P * N_NODES * 64;
    float* y    = (float*)d_ws;           // region kept float-sized; bf16 y uses first half
    float* zz   = y + CH;
    float* aggh = zz + CH;
    float* e    = aggh + CH;
    unsigned short* ybf = (unsigned short*)y;
    unsigned short* zbf = (unsigned short*)zz;
    // y region is dead after k_gather — transformer weight scratch (written by k_emb_ws)
    unsigned short* w1s    = (unsigned short*)y;
    unsigned short* w2s    = w1s + 262144;
    unsigned short* wqkv_s = w2s + 262144;
    unsigned short* tow_s  = wqkv_s + 24576;
    // e region is dead until k_emb_ws — bins (7.68MB) + overflow list
    unsigned short* bins = (unsigned short*)e;
    int* ovf_cnt = (int*)((char*)e + (size_t)N_ROWS * 64);
    int2* ovf    = (int2*)((char*)ovf_cnt + 16);

    hipMemsetAsync(bins, 0, (size_t)N_ROWS * 64 + 16, stream);  // headers + ovf_cnt
    k_phaseA<<<NB_FILL + NB_LIN, 256, 0, stream>>>(ei, bins, ovf_cnt, ovf,
                                                   x, Wl, W0, W1, b0, bl, b1, ybf, zbf);
    k_gather<<<N_ROWS / 4, 256, 0, stream>>>(bins, ovf_cnt, ovf, ybf, aggh);
    k_emb_ws<<<N_NODES / 16 + 1024, 256, 0, stream>>>(aggh, zbf, Wo, bo, mpw, e,
                                                      ff1w, ff2w, tinw, tow,
                                                      w1s, w2s, wqkv_s, tow_s);
    for (int l = 0; l < 2; ++l) {
        k_attn_mfma<<<(N_TOK + 127) / 128, 256, 0, stream>>>(e, wqkv_s, tinb, tow_s, tob,
                                                             ln1g, ln1b, e, l);
        k_ffn_mfma<<<(N_TOK + 127) / 128, 256, 0, stream>>>(e, w1s, w2s, ff1b, ff2b,
                                                            ln2g, ln2b, e, l);
    }
    k_reg<<<N_NODES / 4, 256, 0, stream>>>(e, r1w, r1b, r2w, r2b, (float*)d_out);
}